// Round 7
// baseline (469.574 us; speedup 1.0000x reference)
//
#include <hip/hip_runtime.h>
#include <hip/hip_bf16.h>
#include <hip/hip_cooperative_groups.h>

namespace cg = cooperative_groups;

#define VOCAB   50257
#define NUM_DIM 1024
#define VB 64                              // vocab entries per tile
#define DB 64                              // dims per tile
#define NVCH ((VOCAB + VB - 1) / VB)       // 786 vocab chunks
#define CLCAP 96                           // list capacity per chunk (mean ~21)
#define NDCH (NUM_DIM / DB)                // 16 dim chunks
#define NJOB (NVCH * NDCH)                 // 12576 tile jobs
#define GRID 2048                          // 8 blocks/CU x 256 CU, exactly co-resident

typedef float f32x4 __attribute__((ext_vector_type(4)));  // NT-store-compatible

// ---- one tile job: load weight[d0:d0+64][v0:v0+64] to LDS, emit token slices ----

__device__ __forceinline__ void do_tile_job(
    int cv, int d0, int tid,
    const float* __restrict__ weight, const float* __restrict__ bias,
    const int* __restrict__ ccount, const unsigned* __restrict__ clist,
    float* __restrict__ out,
    float (*tile)[VB + 1], unsigned* slist, int* snn)
{
    int v0 = cv * VB;
    if (tid == 0) { int c = ccount[cv]; *snn = c < CLCAP ? c : CLCAP; }
    if (tid < CLCAP) slist[tid] = clist[cv * CLCAP + tid];

    // tile load: 64 rows x 16 float4-chunks, coalesced along vocab.
    // pointer-increment addressing: one 64-bit setup, then += 16*VOCAB.
    int trow = tid >> 4;                   // 0..15
    int tcol = (tid & 15) << 2;            // 0..60
    const float* gp = weight + (size_t)(d0 + trow) * VOCAB + v0 + tcol;
    if (v0 + VB <= VOCAB) {                // block-uniform fast path (all but cv=785)
        #pragma unroll
        for (int p = 0; p < 4; ++p) {
            float4 w = *reinterpret_cast<const float4*>(gp);
            gp += (size_t)16 * VOCAB;
            int d = trow + (p << 4);
            tile[d][tcol + 0] = w.x;       // 2-way LDS bank aliasing: free
            tile[d][tcol + 1] = w.y;
            tile[d][tcol + 2] = w.z;
            tile[d][tcol + 3] = w.w;
        }
    } else {
        #pragma unroll
        for (int p = 0; p < 4; ++p) {
            int d = trow + (p << 4);
            const float* rowp = weight + (size_t)(d0 + d) * VOCAB;
            #pragma unroll
            for (int k = 0; k < 4; ++k) {
                int v = v0 + tcol + k;
                tile[d][tcol + k] = (v < VOCAB) ? rowp[v] : 0.f;
            }
        }
    }
    __syncthreads();

    // write phase: 16 lanes x 4 dims per token -> float4 NT stores, 16 tokens parallel
    int tl = tid >> 4;
    int c4 = (tid & 15) << 2;
    float4 b4 = *reinterpret_cast<const float4*>(bias + d0 + c4);
    int n = *snn;
    for (int i = tl; i < n; i += 16) {
        unsigned e = slist[i];
        int vl = e & 63;
        size_t t = e >> 6;
        f32x4 o;
        o.x = tile[c4 + 0][vl] + b4.x;
        o.y = tile[c4 + 1][vl] + b4.y;
        o.z = tile[c4 + 2][vl] + b4.z;
        o.w = tile[c4 + 3][vl] + b4.w;
        // non-temporal: out is write-once -> don't evict weight from L3
        __builtin_nontemporal_store(o, reinterpret_cast<f32x4*>(out + t * NUM_DIM + d0 + c4));
    }
}

// ---- fused cooperative kernel: zero -> scatter -> tile jobs, one dispatch ----

__global__ void __launch_bounds__(256, 8) fused_embed(
    const int* __restrict__ tokens, int n_tok,
    const float* __restrict__ weight, const float* __restrict__ bias,
    int* ccount, unsigned* clist, int* n_ov, int* ov_list,
    float* __restrict__ out)
{
    cg::grid_group gg = cg::this_grid();
    __shared__ float tile[DB][VB + 1];     // stride 65: column reads conflict-free
    __shared__ unsigned slist[CLCAP];
    __shared__ int snn;

    int tid = threadIdx.x;
    int bid = blockIdx.x;
    int gid = bid * 256 + tid;

    // phase 0: zero counters
    if (gid < NVCH) ccount[gid] = 0;
    if (gid == 0) *n_ov = 0;
    gg.sync();

    // phase 1: scatter tokens into per-chunk lists
    for (int i = gid; i < n_tok; i += GRID * 256) {
        int v = tokens[i];
        int ch = v >> 6;
        int slot = atomicAdd(&ccount[ch], 1);
        if (slot < CLCAP) clist[ch * CLCAP + slot] = ((unsigned)i << 6) | (unsigned)(v & 63);
        else { int p = atomicAdd(n_ov, 1); ov_list[p] = i; }
    }
    gg.sync();

    // cold overflow path (n_ov == 0 for random tokens): 16 blocks cover 64 dims each
    if (bid < NDCH) {
        int nov = *n_ov;
        if (nov > 0) {
            int d = tid & 63;
            int d0o = bid << 6;
            float b = bias[d0o + d];
            for (int i = tid >> 6; i < nov; i += 4) {
                int t = ov_list[i];
                int v = tokens[t];
                out[(size_t)t * NUM_DIM + d0o + d] = weight[(size_t)(d0o + d) * VOCAB + v] + b;
            }
        }
    }

    // phase 2: persistent blocks over tile jobs, d0-fast order (token-row write bursts)
    for (int j = bid; j < NJOB; j += GRID) {
        __syncthreads();                   // protect LDS reuse across jobs
        do_tile_job(j >> 4, (j & 15) << 6, tid,
                    weight, bias, ccount, clist, out, tile, slist, &snn);
    }
}

// ---------------- non-cooperative fallback path ----------------

__global__ void __launch_bounds__(256) scatter_kernel(
    const int* __restrict__ tokens, int n_tok,
    int* ccount, unsigned* clist, int* n_ov, int* ov_list)
{
    int i = blockIdx.x * 256 + threadIdx.x;
    if (i >= n_tok) return;
    int v = tokens[i];
    int ch = v >> 6;
    int slot = atomicAdd(&ccount[ch], 1);
    if (slot < CLCAP) clist[(size_t)ch * CLCAP + slot] = ((unsigned)i << 6) | (unsigned)(v & 63);
    else { int p = atomicAdd(n_ov, 1); ov_list[p] = i; }
}

__global__ void __launch_bounds__(256, 8) embed_main(
    const float* __restrict__ weight, const float* __restrict__ bias,
    const int* __restrict__ ccount, const unsigned* __restrict__ clist,
    float* __restrict__ out,
    const int* __restrict__ tokens, const int* __restrict__ n_ov,
    const int* __restrict__ ov_list)
{
    __shared__ float tile[DB][VB + 1];
    __shared__ unsigned slist[CLCAP];
    __shared__ int snn;

    int tid = threadIdx.x;
    int cv = blockIdx.y;
    int d0 = blockIdx.x * DB;

    do_tile_job(cv, d0, tid, weight, bias, ccount, clist, out, tile, slist, &snn);

    if (cv == 0) {
        int nov = *n_ov;
        if (nov > 0) {
            int d = tid & 63;
            float b = bias[d0 + d];
            for (int i = tid >> 6; i < nov; i += 4) {
                int t = ov_list[i];
                int v = tokens[t];
                out[(size_t)t * NUM_DIM + d0 + d] = weight[(size_t)(d0 + d) * VOCAB + v] + b;
            }
        }
    }
}

// ---------------- naive fallback if ws too small ----------------

__global__ void __launch_bounds__(256) token_embed_naive(
    const int* __restrict__ tokens, const float* __restrict__ weight,
    const float* __restrict__ bias, float* __restrict__ out, int n_tok)
{
    int t = blockIdx.x;
    if (t >= n_tok) return;
    int tok = tokens[t];
    int dd = threadIdx.x * 4;
    const float* wcol = weight + tok;
    float4 b4 = *reinterpret_cast<const float4*>(bias + dd);
    float4 o;
    o.x = wcol[(size_t)(dd + 0) * VOCAB] + b4.x;
    o.y = wcol[(size_t)(dd + 1) * VOCAB] + b4.y;
    o.z = wcol[(size_t)(dd + 2) * VOCAB] + b4.z;
    o.w = wcol[(size_t)(dd + 3) * VOCAB] + b4.w;
    *reinterpret_cast<float4*>(out + (size_t)t * NUM_DIM + dd) = o;
}

extern "C" void kernel_launch(void* const* d_in, const int* in_sizes, int n_in,
                              void* d_out, int out_size, void* d_ws, size_t ws_size,
                              hipStream_t stream)
{
    const int*   tokens = (const int*)d_in[0];
    const float* weight = (const float*)d_in[1];
    const float* bias   = (const float*)d_in[2];
    float*       out    = (float*)d_out;
    int n_tok = in_sizes[0];               // 16384

    // ws layout (ints): ccount[NVCH] | n_ov[64] | ov_list[n_tok] | clist[NVCH*CLCAP]
    size_t need_ints = (size_t)NVCH + 64 + (size_t)n_tok + (size_t)NVCH * CLCAP;
    if (ws_size < need_ints * sizeof(int)) {
        token_embed_naive<<<n_tok, 256, 0, stream>>>(tokens, weight, bias, out, n_tok);
        return;
    }

    int*      ccount  = (int*)d_ws;
    int*      n_ov    = ccount + NVCH;
    int*      ov_list = n_ov + 64;
    unsigned* clist   = (unsigned*)(ov_list + n_tok);

    void* kargs[] = { (void*)&tokens, (void*)&n_tok, (void*)&weight, (void*)&bias,
                      (void*)&ccount, (void*)&clist, (void*)&n_ov, (void*)&ov_list,
                      (void*)&out };
    hipError_t err = hipLaunchCooperativeKernel((const void*)fused_embed,
                                                dim3(GRID), dim3(256), kargs, 0u, stream);
    if (err == hipSuccess) return;

    // fallback: 3-dispatch chain (round-6 structure)
    (void)hipMemsetAsync(ccount, 0, (size_t)(NVCH + 64) * sizeof(int), stream);
    scatter_kernel<<<(n_tok + 255) / 256, 256, 0, stream>>>(
        tokens, n_tok, ccount, clist, n_ov, ov_list);
    dim3 grid(NDCH, NVCH);
    embed_main<<<grid, 256, 0, stream>>>(weight, bias, ccount, clist, out,
                                         tokens, n_ov, ov_list);
}

// Round 8
// 60.997 us; speedup vs baseline: 7.6984x; 7.6984x over previous
//
#include <hip/hip_runtime.h>
#include <hip/hip_bf16.h>

#define VOCAB   50257
#define NUM_DIM 1024
#define VB 64                              // vocab entries per tile
#define DB 64                              // dims per tile
#define DSTR (DB + 4)                      // tile row stride: 68 floats = 272B, 16B-aligned
#define NVCH ((VOCAB + VB - 1) / VB)       // 786 vocab chunks
#define CLCAP 96                           // list capacity per chunk (mean ~21)
#define NDCH (NUM_DIM / DB)                // 16 dim chunks

typedef float f32x4 __attribute__((ext_vector_type(4)));  // NT-store-compatible

// ---------------- scatter: bucket tokens by vocab chunk ----------------

__global__ void __launch_bounds__(256) scatter_kernel(
    const int* __restrict__ tokens, int n_tok,
    int* ccount, unsigned* clist, int* n_ov, int* ov_list)
{
    int i = blockIdx.x * 256 + threadIdx.x;
    if (i >= n_tok) return;
    int v = tokens[i];
    int ch = v >> 6;                                   // vocab chunk (VB=64)
    int slot = atomicAdd(&ccount[ch], 1);
    if (slot < CLCAP) clist[ch * CLCAP + slot] = ((unsigned)i << 6) | (unsigned)(v & 63);
    else { int p = atomicAdd(n_ov, 1); ov_list[p] = i; }
}

// ---------------- main: stream weight once, scatter to output rows ----------------
// grid(NDCH, NVCH): d-chunk is the FAST dispatch axis (token-row write bursts).
// TRANSPOSED tile[v][d] (stride 68): write phase = one ds_read_b128 per
// token-slice (was 4x strided ds_read_b32 with ~4-way conflicts).

__global__ void __launch_bounds__(256, 8) embed_main(
    const float* __restrict__ weight, const float* __restrict__ bias,
    const int* __restrict__ ccount, const unsigned* __restrict__ clist,
    float* __restrict__ out,
    const int* __restrict__ tokens, const int* __restrict__ n_ov,
    const int* __restrict__ ov_list)
{
    __shared__ float tile[VB][DSTR];       // tile[v][d]
    __shared__ unsigned slist[CLCAP];
    __shared__ int snn;

    int tid = threadIdx.x;
    int cv = blockIdx.y;
    int v0 = cv * VB;
    int d0 = blockIdx.x * DB;

    if (tid == 0) { int c = ccount[cv]; snn = c < CLCAP ? c : CLCAP; }
    if (tid < CLCAP) slist[tid] = clist[cv * CLCAP + tid];

    // tile load: coalesced float4 along vocab, transposed scatter into LDS.
    // banks: (4*(tcol+k) + trow + 16p) mod 32 -> 2-way per instr (free).
    int trow = tid >> 4;                   // d-offset base 0..15
    int tcol = (tid & 15) << 2;            // v-offset 0..60
    const float* gp = weight + (size_t)(d0 + trow) * VOCAB + v0 + tcol;
    if (v0 + VB <= VOCAB) {                // block-uniform fast path (all but cv=785)
        #pragma unroll
        for (int p = 0; p < 4; ++p) {
            float4 w = *reinterpret_cast<const float4*>(gp);
            gp += (size_t)16 * VOCAB;
            int d = trow + (p << 4);
            tile[tcol + 0][d] = w.x;
            tile[tcol + 1][d] = w.y;
            tile[tcol + 2][d] = w.z;
            tile[tcol + 3][d] = w.w;
        }
    } else {
        #pragma unroll
        for (int p = 0; p < 4; ++p) {
            int d = trow + (p << 4);
            const float* rowp = weight + (size_t)(d0 + d) * VOCAB;
            #pragma unroll
            for (int k = 0; k < 4; ++k) {
                int v = v0 + tcol + k;
                tile[tcol + k][d] = (v < VOCAB) ? rowp[v] : 0.f;
            }
        }
    }
    __syncthreads();

    // write phase: 16 lanes x 4 dims per token; one ds_read_b128 + one NT
    // global_store_dwordx4 per token-slice; 16 tokens in parallel.
    int tl = tid >> 4;                     // token slot group 0..15
    int dc = (tid & 15) << 2;              // dim offset within tile
    float4 b4 = *reinterpret_cast<const float4*>(bias + d0 + dc);
    int n = snn;
    for (int i = tl; i < n; i += 16) {
        unsigned e = slist[i];
        int vl = e & 63;
        size_t t = e >> 6;
        float4 w4 = *reinterpret_cast<const float4*>(&tile[vl][dc]);  // b128, aligned
        f32x4 o;
        o.x = w4.x + b4.x;
        o.y = w4.y + b4.y;
        o.z = w4.z + b4.z;
        o.w = w4.w + b4.w;
        // non-temporal: out is write-once -> don't evict weight from L3
        __builtin_nontemporal_store(o, reinterpret_cast<f32x4*>(out + t * NUM_DIM + d0 + dc));
    }

    // cold overflow path (n_ov == 0 for random tokens): cv==0 blocks cover it
    if (cv == 0) {
        int nov = *n_ov;
        if (nov > 0) {
            int d = tid & 63;
            float b = bias[d0 + d];
            for (int i = tid >> 6; i < nov; i += 4) {
                int t = ov_list[i];
                int v = tokens[t];
                out[(size_t)t * NUM_DIM + d0 + d] = weight[(size_t)(d0 + d) * VOCAB + v] + b;
            }
        }
    }
}

// ---------------- naive fallback if ws too small ----------------

__global__ void __launch_bounds__(256) token_embed_naive(
    const int* __restrict__ tokens, const float* __restrict__ weight,
    const float* __restrict__ bias, float* __restrict__ out, int n_tok)
{
    int t = blockIdx.x;
    if (t >= n_tok) return;
    int tok = tokens[t];
    int dd = threadIdx.x * 4;
    const float* wcol = weight + tok;
    float4 b4 = *reinterpret_cast<const float4*>(bias + dd);
    float4 o;
    o.x = wcol[(size_t)(dd + 0) * VOCAB] + b4.x;
    o.y = wcol[(size_t)(dd + 1) * VOCAB] + b4.y;
    o.z = wcol[(size_t)(dd + 2) * VOCAB] + b4.z;
    o.w = wcol[(size_t)(dd + 3) * VOCAB] + b4.w;
    *reinterpret_cast<float4*>(out + (size_t)t * NUM_DIM + dd) = o;
}

extern "C" void kernel_launch(void* const* d_in, const int* in_sizes, int n_in,
                              void* d_out, int out_size, void* d_ws, size_t ws_size,
                              hipStream_t stream)
{
    const int*   tokens = (const int*)d_in[0];
    const float* weight = (const float*)d_in[1];
    const float* bias   = (const float*)d_in[2];
    float*       out    = (float*)d_out;
    int n_tok = in_sizes[0];               // 16384

    // ws layout (ints): ccount[NVCH] | n_ov[64] | ov_list[n_tok] | clist[NVCH*CLCAP]
    size_t need_ints = (size_t)NVCH + 64 + (size_t)n_tok + (size_t)NVCH * CLCAP;
    if (ws_size < need_ints * sizeof(int)) {
        token_embed_naive<<<n_tok, 256, 0, stream>>>(tokens, weight, bias, out, n_tok);
        return;
    }

    int*      ccount  = (int*)d_ws;
    int*      n_ov    = ccount + NVCH;
    int*      ov_list = n_ov + 64;
    unsigned* clist   = (unsigned*)(ov_list + n_tok);

    // zero ccount + n_ov in one capturable memset (they are adjacent)
    (void)hipMemsetAsync(ccount, 0, (size_t)(NVCH + 64) * sizeof(int), stream);

    scatter_kernel<<<(n_tok + 255) / 256, 256, 0, stream>>>(
        tokens, n_tok, ccount, clist, n_ov, ov_list);

    dim3 grid(NDCH, NVCH);                 // (16, 786): d-chunk fast axis
    embed_main<<<grid, 256, 0, stream>>>(weight, bias, ccount, clist, out,
                                         tokens, n_ov, ov_list);
}

// Round 9
// 60.420 us; speedup vs baseline: 7.7718x; 1.0095x over previous
//
#include <hip/hip_runtime.h>
#include <hip/hip_bf16.h>

#define VOCAB   50257
#define NUM_DIM 1024
#define VB 64                              // vocab entries per tile
#define DB 64                              // dims per tile
#define NVCH ((VOCAB + VB - 1) / VB)       // 786 vocab chunks
#define CLCAP 96                           // list capacity per chunk (mean ~21)
#define NDCH (NUM_DIM / DB)                // 16 dim chunks

typedef float f32x4 __attribute__((ext_vector_type(4)));  // NT-store-compatible

// Swizzled flat tile, 16KB: offset(v,d) = v*64 + (((d>>2)+(v>>2))&15)*4 + (d&3)
//  - load phase (scalar stores, v=4m+k, d=trow+16p): bank = (4*((dq+m)&15) + d&3) mod 32
//    -> m bijective over 0..15 -> exactly 2 lanes/bank (free)
//  - write phase (b128 reads, 16 lanes span g=0..15 at fixed vl): s=(g+(vl>>2))&15
//    covers the full row -> uniform 2x/bank (free), 16B-aligned

// ---------------- scatter: bucket tokens by vocab chunk ----------------

__global__ void __launch_bounds__(256) scatter_kernel(
    const int* __restrict__ tokens, int n_tok,
    int* ccount, unsigned* clist, int* n_ov, int* ov_list)
{
    int i = blockIdx.x * 256 + threadIdx.x;
    if (i >= n_tok) return;
    int v = tokens[i];
    int ch = v >> 6;                                   // vocab chunk (VB=64)
    int slot = atomicAdd(&ccount[ch], 1);
    if (slot < CLCAP) clist[ch * CLCAP + slot] = ((unsigned)i << 6) | (unsigned)(v & 63);
    else { int p = atomicAdd(n_ov, 1); ov_list[p] = i; }
}

// ---------------- main: stream weight once, scatter to output rows ----------------

__global__ void __launch_bounds__(256, 8) embed_main(
    const float* __restrict__ weight, const float* __restrict__ bias,
    const int* __restrict__ ccount, const unsigned* __restrict__ clist,
    float* __restrict__ out,
    const int* __restrict__ tokens, const int* __restrict__ n_ov,
    const int* __restrict__ ov_list)
{
    __shared__ __align__(16) float tile[VB * DB];   // swizzled, 16 KB
    __shared__ unsigned slist[CLCAP];
    __shared__ int snn;

    int tid = threadIdx.x;
    int cv = blockIdx.y;
    int v0 = cv * VB;
    int d0 = blockIdx.x * DB;

    if (tid == 0) { int c = ccount[cv]; snn = c < CLCAP ? c : CLCAP; }
    if (tid < CLCAP) slist[tid] = clist[cv * CLCAP + tid];

    // tile load: coalesced float4 along vocab, swizzled scatter into LDS
    int trow = tid >> 4;                   // d-offset base 0..15
    int m    = tid & 15;                   // v-group index (v>>2 for this thread)
    int tcol = m << 2;                     // v-offset 0..60
    const float* gp = weight + (size_t)(d0 + trow) * VOCAB + v0 + tcol;
    if (v0 + VB <= VOCAB) {                // block-uniform fast path (all but cv=785)
        #pragma unroll
        for (int p = 0; p < 4; ++p) {
            float4 w = *reinterpret_cast<const float4*>(gp);
            gp += (size_t)16 * VOCAB;
            int d = trow + (p << 4);
            int o = tcol * 64 + ((((d >> 2) + m) & 15) << 2) + (d & 3);
            tile[o + 0 * 64] = w.x;        // v = 4m+0..3: 2 lanes/bank (free)
            tile[o + 1 * 64] = w.y;
            tile[o + 2 * 64] = w.z;
            tile[o + 3 * 64] = w.w;
        }
    } else {
        #pragma unroll
        for (int p = 0; p < 4; ++p) {
            int d = trow + (p << 4);
            const float* rowp = weight + (size_t)(d0 + d) * VOCAB;
            int o = tcol * 64 + ((((d >> 2) + m) & 15) << 2) + (d & 3);
            #pragma unroll
            for (int k = 0; k < 4; ++k) {
                int v = v0 + tcol + k;
                tile[o + k * 64] = (v < VOCAB) ? rowp[v] : 0.f;
            }
        }
    }
    __syncthreads();

    // write phase: 16 lanes x 4 dims per token; one b128 read + one NT dwordx4
    int tl = tid >> 4;                     // token slot group 0..15
    int g  = tid & 15;                     // d-group 0..15
    float4 b4 = *reinterpret_cast<const float4*>(bias + d0 + (g << 2));
    int n = snn;
    for (int i = tl; i < n; i += 16) {
        unsigned e = slist[i];
        int vl = e & 63;
        size_t t = e >> 6;
        int s = ((g + (vl >> 2)) & 15) << 2;
        float4 w4 = *reinterpret_cast<const float4*>(&tile[vl * 64 + s]);
        f32x4 o;
        o.x = w4.x + b4.x;
        o.y = w4.y + b4.y;
        o.z = w4.z + b4.z;
        o.w = w4.w + b4.w;
        // non-temporal: out is write-once -> don't evict weight from L3
        __builtin_nontemporal_store(o, reinterpret_cast<f32x4*>(out + t * NUM_DIM + d0 + (g << 2)));
    }

    // cold overflow path (n_ov == 0 for random tokens): cv==0 blocks cover it
    if (cv == 0) {
        int nov = *n_ov;
        if (nov > 0) {
            int d = tid & 63;
            float b = bias[d0 + d];
            for (int i = tid >> 6; i < nov; i += 4) {
                int t = ov_list[i];
                int v = tokens[t];
                out[(size_t)t * NUM_DIM + d0 + d] = weight[(size_t)(d0 + d) * VOCAB + v] + b;
            }
        }
    }
}

// ---------------- naive fallback if ws too small ----------------

__global__ void __launch_bounds__(256) token_embed_naive(
    const int* __restrict__ tokens, const float* __restrict__ weight,
    const float* __restrict__ bias, float* __restrict__ out, int n_tok)
{
    int t = blockIdx.x;
    if (t >= n_tok) return;
    int tok = tokens[t];
    int dd = threadIdx.x * 4;
    const float* wcol = weight + tok;
    float4 b4 = *reinterpret_cast<const float4*>(bias + dd);
    float4 o;
    o.x = wcol[(size_t)(dd + 0) * VOCAB] + b4.x;
    o.y = wcol[(size_t)(dd + 1) * VOCAB] + b4.y;
    o.z = wcol[(size_t)(dd + 2) * VOCAB] + b4.z;
    o.w = wcol[(size_t)(dd + 3) * VOCAB] + b4.w;
    *reinterpret_cast<float4*>(out + (size_t)t * NUM_DIM + dd) = o;
}

extern "C" void kernel_launch(void* const* d_in, const int* in_sizes, int n_in,
                              void* d_out, int out_size, void* d_ws, size_t ws_size,
                              hipStream_t stream)
{
    const int*   tokens = (const int*)d_in[0];
    const float* weight = (const float*)d_in[1];
    const float* bias   = (const float*)d_in[2];
    float*       out    = (float*)d_out;
    int n_tok = in_sizes[0];               // 16384

    // ws layout (ints): ccount[NVCH] | n_ov[64] | ov_list[n_tok] | clist[NVCH*CLCAP]
    size_t need_ints = (size_t)NVCH + 64 + (size_t)n_tok + (size_t)NVCH * CLCAP;
    if (ws_size < need_ints * sizeof(int)) {
        token_embed_naive<<<n_tok, 256, 0, stream>>>(tokens, weight, bias, out, n_tok);
        return;
    }

    int*      ccount  = (int*)d_ws;
    int*      n_ov    = ccount + NVCH;
    int*      ov_list = n_ov + 64;
    unsigned* clist   = (unsigned*)(ov_list + n_tok);

    // zero ccount + n_ov in one capturable memset (they are adjacent)
    (void)hipMemsetAsync(ccount, 0, (size_t)(NVCH + 64) * sizeof(int), stream);

    scatter_kernel<<<(n_tok + 255) / 256, 256, 0, stream>>>(
        tokens, n_tok, ccount, clist, n_ov, ov_list);

    dim3 grid(NDCH, NVCH);                 // (16, 786): d-chunk fast axis
    embed_main<<<grid, 256, 0, stream>>>(weight, bias, ccount, clist, out,
                                         tokens, n_ov, ov_list);
}